// Round 4
// baseline (893.999 us; speedup 1.0000x reference)
//
#include <hip/hip_runtime.h>

typedef _Float16 f16;
typedef __attribute__((ext_vector_type(8))) _Float16 f16x8;
typedef __attribute__((ext_vector_type(4))) _Float16 f16x4;
typedef __attribute__((ext_vector_type(4))) float f32x4;

constexpr int B_ = 8, LQ = 1024, LK = 2048, NH = 16, HID = 1024;

// async global->LDS, 16B per lane; LDS dest must be wave-uniform base + lane*16
__device__ __forceinline__ void gll16(const void* g, void* l) {
  __builtin_amdgcn_global_load_lds((const __attribute__((address_space(1))) void*)g,
                                   (__attribute__((address_space(3))) void*)l, 16, 0, 0);
}

// DPP cross-lane helpers (no DS traffic)
__device__ __forceinline__ float rowmax16(float x) {
  float y;
  y = __int_as_float(__builtin_amdgcn_update_dpp(0, __float_as_int(x), 0x128, 0xf, 0xf, true)); // row_ror:8
  x = fmaxf(x, y);
  y = __int_as_float(__builtin_amdgcn_update_dpp(0, __float_as_int(x), 0x124, 0xf, 0xf, true)); // row_ror:4
  x = fmaxf(x, y);
  y = __int_as_float(__builtin_amdgcn_update_dpp(0, __float_as_int(x), 0x4E, 0xf, 0xf, true));  // quad_perm 2,3,0,1
  x = fmaxf(x, y);
  y = __int_as_float(__builtin_amdgcn_update_dpp(0, __float_as_int(x), 0xB1, 0xf, 0xf, true));  // quad_perm 1,0,3,2
  x = fmaxf(x, y);
  return x;
}
__device__ __forceinline__ float shx1(float x) {  // lane ^ 1
  return __int_as_float(__builtin_amdgcn_update_dpp(0, __float_as_int(x), 0xB1, 0xf, 0xf, true));
}

// ---------- fused fp32 -> fp16 cast for all 5 inputs ----------
__global__ __launch_bounds__(256) void cvt_all(const float* __restrict__ x, const float* __restrict__ y,
                                               const float* __restrict__ wq, const float* __restrict__ wkv,
                                               const float* __restrict__ wo, f16* __restrict__ xb,
                                               f16* __restrict__ yb, f16* __restrict__ wqb,
                                               f16* __restrict__ wkvb, f16* __restrict__ wob) {
  int t = blockIdx.x * 256 + threadIdx.x;  // in float4 units, total 7340032
  const float* s;
  f16* d;
  int off;
  if (t < 2097152) { s = x; d = xb; off = t; }
  else if (t < 6291456) { s = y; d = yb; off = t - 2097152; }
  else if (t < 6553600) { s = wq; d = wqb; off = t - 6291456; }
  else if (t < 7077888) { s = wkv; d = wkvb; off = t - 6553600; }
  else { s = wo; d = wob; off = t - 7077888; }
  float4 v = ((const float4*)s)[off];
  f16x4 o = {(f16)v.x, (f16)v.y, (f16)v.z, (f16)v.w};
  ((f16x4*)d)[off] = o;
}

// ---------- RoPE trig tables: tabQ = log2e*(cos,sin), tabK = (cos,sin) ----------
__global__ __launch_bounds__(256) void rope_tab(float2* __restrict__ tabQ, float2* __restrict__ tabK) {
  int t = blockIdx.x * 256 + threadIdx.x;  // 2048*32
  int pos = t >> 5, i = t & 31;
  float inv_t = exp2f((float)i * -0.41524101186091903f);
  float sn, cs;
  sincosf((float)pos * inv_t, &sn, &cs);
  tabK[t] = make_float2(cs, sn);
  const float L2E = 1.4426950408889634f;
  tabQ[t] = make_float2(cs * L2E, sn * L2E);
}

// ---------- fused NT GEMM: C[M,N] = A[M,K] * B[N,K]^T ----------
// MODE 0: Q proj -> RoPE (tab=tabQ, log2e-folded) -> Qb [bh][lq][64]
// MODE 1: KV proj -> wn=0: RoPE K (tab=tabK) -> Kb [bh][lk][64]; wn=1: V^T -> Vt [bh][kc][dv][64]
// MODE 2: plain fp32 output
template <int MODE>
__global__ __launch_bounds__(256) void gemm_fused(const f16* __restrict__ A,
                                                  const f16* __restrict__ Bm,
                                                  void* __restrict__ out0,
                                                  void* __restrict__ out1,
                                                  const float2* __restrict__ tab,
                                                  int M, int N, int K) {
  const int n0 = blockIdx.x * 128, m0 = blockIdx.y * 128;
  const int tid = threadIdx.x, lane = tid & 63, w = tid >> 6;
  const int wm = w >> 1, wn = w & 1;
  const int quad = lane >> 4, l16 = lane & 15;
  __shared__ __align__(16) f16 As[128 * 64];
  __shared__ __align__(16) f16 Bs[128 * 64];
  f32x4 acc[4][4] = {};
  const int sr = tid >> 3, sc = (tid & 7) * 8;
  const f16* ga = A + (size_t)(m0 + sr) * K + sc;
  const f16* gb = Bm + (size_t)(n0 + sr) * K + sc;
  for (int k0 = 0; k0 < K; k0 += 64) {
    __syncthreads();
#pragma unroll
    for (int p = 0; p < 4; ++p) {
      gll16(ga + (size_t)p * 32 * K + k0, &As[(sr + p * 32) * 64 + sc]);
      gll16(gb + (size_t)p * 32 * K + k0, &Bs[(sr + p * 32) * 64 + sc]);
    }
    __syncthreads();
#pragma unroll
    for (int ks = 0; ks < 2; ++ks) {
      f16x8 af[4], bfr[4];
#pragma unroll
      for (int i = 0; i < 4; ++i) {
        af[i] = *(const f16x8*)&As[(wm * 64 + i * 16 + l16) * 64 + ks * 32 + quad * 8];
        bfr[i] = *(const f16x8*)&Bs[(wn * 64 + i * 16 + l16) * 64 + ks * 32 + quad * 8];
      }
#pragma unroll
      for (int i = 0; i < 4; ++i)
#pragma unroll
        for (int j = 0; j < 4; ++j)
          acc[i][j] = __builtin_amdgcn_mfma_f32_16x16x32_f16(af[i], bfr[j], acc[i][j], 0, 0, 0);
    }
  }
  if (MODE == 2) {
#pragma unroll
    for (int i = 0; i < 4; ++i)
#pragma unroll
      for (int j = 0; j < 4; ++j) {
        int row = m0 + wm * 64 + i * 16 + quad * 4;
        int col = n0 + wn * 64 + j * 16 + l16;
#pragma unroll
        for (int r = 0; r < 4; ++r)
          ((float*)out0)[(size_t)(row + r) * N + col] = acc[i][j][r];
      }
    return;
  }
  constexpr int LSH = (MODE == 0) ? 10 : 11;
  constexpr int LMSK = (MODE == 0) ? 1023 : 2047;
  const int Ltok = LMSK + 1;
  if (MODE == 0 || wn == 0) {
    // RoPE path via table
#pragma unroll
    for (int j = 0; j < 4; ++j) {
      int c = n0 + wn * 64 + j * 16 + l16;
      int h = (MODE == 0) ? (c >> 6) : (n0 >> 7);
      int d = (MODE == 0) ? (c & 63) : (j * 16 + l16);
      const float2* tcol = tab + (d >> 1);
#pragma unroll
      for (int i = 0; i < 4; ++i) {
        f32x4 v = acc[i][j];
        f32x4 pv;
#pragma unroll
        for (int r = 0; r < 4; ++r) pv[r] = shx1(v[r]);
        int row0 = m0 + wm * 64 + i * 16 + quad * 4;
#pragma unroll
        for (int r = 0; r < 4; ++r) {
          int row = row0 + r;
          int pos = row & LMSK, b = row >> LSH;
          float2 t = tcol[pos * 32];
          float o = (d & 1) ? (v[r] * t.x + pv[r] * t.y) : (v[r] * t.x - pv[r] * t.y);
          ((f16*)out0)[(((size_t)b * NH + h) * Ltok + pos) * 64 + d] = (f16)o;
        }
      }
    }
  } else {
    // V path: write V^T tiled: Vt[((bh*32 + kc)*64 + dv)*64 + klo]
    const int h = n0 >> 7;
#pragma unroll
    for (int j = 0; j < 4; ++j) {
      int dv = j * 16 + l16;
#pragma unroll
      for (int i = 0; i < 4; ++i) {
        int row0 = m0 + wm * 64 + i * 16 + quad * 4;
        int pos0 = row0 & 2047, b = row0 >> 11;
        int kc = pos0 >> 6, klo = pos0 & 63;
        f32x4 v = acc[i][j];
        f16x4 pk = {(f16)v[0], (f16)v[1], (f16)v[2], (f16)v[3]};
        *(f16x4*)&((f16*)out1)[((((size_t)b * NH + h) * 32 + kc) * 64 + dv) * 64 + klo] = pk;
      }
    }
  }
}

// ---------- flash attention ----------
// 1D grid of 1024 blocks, XCD-swizzled: bh = blk & 127, q-tile = blk >> 7.
// Same-bh blocks are 128 apart -> same XCD (id%8 invariant) -> shared L2 K/V stream.
// 4 waves; each wave: 2 q-tiles of 16 rows (128 q-rows/block).
// Qb pre-scaled by log2e; softmax in exp2 domain. LDS 27.6 KB -> 5 blocks/CU.
__global__ __launch_bounds__(256, 5) void attn(const f16* __restrict__ Qb,
                                               const f16* __restrict__ Kb,
                                               const f16* __restrict__ Vt,
                                               f16* __restrict__ attnb) {
  const int bh = blockIdx.x & 127, b = bh >> 4, h = bh & 15;
  const int q0 = (blockIdx.x >> 7) * 128;
  const int tid = threadIdx.x, lane = tid & 63, w = tid >> 6;
  const int quad = lane >> 4, l16 = lane & 15;
  __shared__ __align__(16) f16 Ks[64 * 72];
  __shared__ __align__(16) f16 Vts[64 * 72];
  __shared__ __align__(16) f16 Ps[4][16 * 72];  // one slot per wave, reused by both q-tiles
  const f16* qp = Qb + ((size_t)bh * LQ + q0 + w * 32 + l16) * 64;
  f16x8 qa0 = *(const f16x8*)&qp[quad * 8];
  f16x8 qa1 = *(const f16x8*)&qp[32 + quad * 8];
  f16x8 qb0 = *(const f16x8*)&qp[16 * 64 + quad * 8];
  f16x8 qb1 = *(const f16x8*)&qp[16 * 64 + 32 + quad * 8];
  f16x8 onesv;
#pragma unroll
  for (int j = 0; j < 8; ++j) onesv[j] = (f16)1.0f;
  f32x4 o0[4] = {}, o1[4] = {};
  f32x4 la0 = {}, la1 = {};
  float mr0[4], mr1[4];
#pragma unroll
  for (int r = 0; r < 4; ++r) { mr0[r] = -1e30f; mr1[r] = -1e30f; }
  const f16* kbase = Kb + (size_t)bh * LK * 64;
  const f16* vtb = Vt + (size_t)bh * 32 * 4096;

  for (int c = 0; c < LK / 64; ++c) {
    int kc0 = c * 64;
    __syncthreads();
#pragma unroll
    for (int p = 0; p < 2; ++p) {
      int r = (tid >> 3) + p * 32, s = tid & 7;
      *(uint4*)&Ks[r * 72 + s * 8] = *(const uint4*)&kbase[(size_t)(kc0 + r) * 64 + s * 8];
      *(uint4*)&Vts[r * 72 + s * 8] = *(const uint4*)&vtb[(size_t)(c * 64 + r) * 64 + s * 8];
    }
    __syncthreads();
    // S = Q K^T for both q-tiles, sharing K fragments
    f32x4 s0[4] = {}, s1[4] = {};
#pragma unroll
    for (int nt = 0; nt < 4; ++nt) {
      f16x8 kf0 = *(const f16x8*)&Ks[(nt * 16 + l16) * 72 + quad * 8];
      f16x8 kf1 = *(const f16x8*)&Ks[(nt * 16 + l16) * 72 + 32 + quad * 8];
      s0[nt] = __builtin_amdgcn_mfma_f32_16x16x32_f16(qa0, kf0, s0[nt], 0, 0, 0);
      s0[nt] = __builtin_amdgcn_mfma_f32_16x16x32_f16(qa1, kf1, s0[nt], 0, 0, 0);
      s1[nt] = __builtin_amdgcn_mfma_f32_16x16x32_f16(qb0, kf0, s1[nt], 0, 0, 0);
      s1[nt] = __builtin_amdgcn_mfma_f32_16x16x32_f16(qb1, kf1, s1[nt], 0, 0, 0);
    }
    // online softmax (exp2 domain), C/D layout: row=quad*4+r, col=nt*16+l16
    auto softmax = [&](f32x4* s, float* mr, f32x4& la, f32x4* o) {
#pragma unroll
      for (int r = 0; r < 4; ++r) {
        float mx = fmaxf(fmaxf(s[0][r], s[1][r]), fmaxf(s[2][r], s[3][r]));
        mx = rowmax16(mx);
        if (mx > mr[r]) {
          float al = exp2f(mr[r] - mx);
          mr[r] = mx;
          la[r] *= al;
#pragma unroll
          for (int dt = 0; dt < 4; ++dt) o[dt][r] *= al;
        }
#pragma unroll
        for (int nt = 0; nt < 4; ++nt)
          Ps[w][(quad * 4 + r) * 72 + nt * 16 + l16] = (f16)exp2f(s[nt][r] - mr[r]);
      }
    };
    // tile 0: write P, read frags (same LDS slot reused for tile 1 after)
    softmax(s0, mr0, la0, o0);
    f16x8 p00 = *(const f16x8*)&Ps[w][l16 * 72 + quad * 8];
    f16x8 p01 = *(const f16x8*)&Ps[w][l16 * 72 + 32 + quad * 8];
    softmax(s1, mr1, la1, o1);
    f16x8 p10 = *(const f16x8*)&Ps[w][l16 * 72 + quad * 8];
    f16x8 p11 = *(const f16x8*)&Ps[w][l16 * 72 + 32 + quad * 8];
    // row sums via ones-MFMA (same C/D layout as o)
    la0 = __builtin_amdgcn_mfma_f32_16x16x32_f16(p00, onesv, la0, 0, 0, 0);
    la0 = __builtin_amdgcn_mfma_f32_16x16x32_f16(p01, onesv, la0, 0, 0, 0);
    la1 = __builtin_amdgcn_mfma_f32_16x16x32_f16(p10, onesv, la1, 0, 0, 0);
    la1 = __builtin_amdgcn_mfma_f32_16x16x32_f16(p11, onesv, la1, 0, 0, 0);
    // O += P V, sharing V fragments across both q-tiles
#pragma unroll
    for (int dt = 0; dt < 4; ++dt) {
      f16x8 vf0 = *(const f16x8*)&Vts[(dt * 16 + l16) * 72 + quad * 8];
      f16x8 vf1 = *(const f16x8*)&Vts[(dt * 16 + l16) * 72 + 32 + quad * 8];
      o0[dt] = __builtin_amdgcn_mfma_f32_16x16x32_f16(p00, vf0, o0[dt], 0, 0, 0);
      o0[dt] = __builtin_amdgcn_mfma_f32_16x16x32_f16(p01, vf1, o0[dt], 0, 0, 0);
      o1[dt] = __builtin_amdgcn_mfma_f32_16x16x32_f16(p10, vf0, o1[dt], 0, 0, 0);
      o1[dt] = __builtin_amdgcn_mfma_f32_16x16x32_f16(p11, vf1, o1[dt], 0, 0, 0);
    }
  }
#pragma unroll
  for (int dt = 0; dt < 4; ++dt)
#pragma unroll
    for (int r = 0; r < 4; ++r) {
      int qA = q0 + w * 32 + quad * 4 + r;
      int dv = dt * 16 + l16;
      attnb[((size_t)b * LQ + qA) * HID + h * 64 + dv] = (f16)(o0[dt][r] / la0[r]);
      attnb[((size_t)b * LQ + qA + 16) * HID + h * 64 + dv] = (f16)(o1[dt][r] / la1[r]);
    }
}

extern "C" void kernel_launch(void* const* d_in, const int* in_sizes, int n_in,
                              void* d_out, int out_size, void* d_ws, size_t ws_size,
                              hipStream_t stream) {
  const float* x = (const float*)d_in[0];
  const float* y = (const float*)d_in[1];
  const float* Wq = (const float*)d_in[2];
  const float* Wkv = (const float*)d_in[3];
  const float* Wo = (const float*)d_in[4];
  float* out = (float*)d_out;

  char* p = (char*)d_ws;
  f16* xb = (f16*)p;    p += (size_t)B_ * LQ * HID * 2;      // 16 MB
  f16* yb = (f16*)p;    p += (size_t)B_ * LK * HID * 2;      // 32 MB
  f16* Wqb = (f16*)p;   p += (size_t)HID * HID * 2;          // 2 MB
  f16* Wkvb = (f16*)p;  p += (size_t)2 * HID * HID * 2;      // 4 MB
  f16* Wob = (f16*)p;   p += (size_t)HID * HID * 2;          // 2 MB
  f16* Qb = (f16*)p;    p += (size_t)B_ * LQ * HID * 2;      // 16 MB
  f16* Kb = (f16*)p;    p += (size_t)B_ * LK * HID * 2;      // 32 MB
  f16* Vt = (f16*)p;    p += (size_t)B_ * LK * HID * 2;      // 32 MB
  f16* attnb = xb;  // xb dead after GEMM1
  // RoPE tables live in d_out scratch (dead before the final GEMM overwrites d_out)
  float2* tabQ = (float2*)d_out;
  float2* tabK = tabQ + 2048 * 32;

  cvt_all<<<dim3(28672), 256, 0, stream>>>(x, y, Wq, Wkv, Wo, xb, yb, Wqb, Wkvb, Wob);
  rope_tab<<<dim3(256), 256, 0, stream>>>(tabQ, tabK);

  // Q = RoPE(x @ Wq^T) * log2e -> Qb [bh][lq][64]
  gemm_fused<0><<<dim3(HID / 128, B_ * LQ / 128), 256, 0, stream>>>(
      xb, Wqb, Qb, nullptr, tabQ, B_ * LQ, HID, HID);
  // KV = y @ Wkv^T -> Kb (RoPE) + Vt (transposed, chunk-tiled)
  gemm_fused<1><<<dim3(2 * HID / 128, B_ * LK / 128), 256, 0, stream>>>(
      yb, Wkvb, Kb, Vt, tabK, B_ * LK, 2 * HID, HID);

  // attention -> attnb [B*LQ, 1024] fp16, XCD-swizzled 1D grid
  attn<<<dim3(1024), 256, 0, stream>>>(Qb, Kb, Vt, attnb);

  // out = attn @ Wo^T -> fp32
  gemm_fused<2><<<dim3(HID / 128, B_ * LQ / 128), 256, 0, stream>>>(
      attnb, Wob, out, nullptr, nullptr, B_ * LQ, HID, HID);
}

// Round 5
// 528.123 us; speedup vs baseline: 1.6928x; 1.6928x over previous
//
#include <hip/hip_runtime.h>

typedef _Float16 f16;
typedef __attribute__((ext_vector_type(8))) _Float16 f16x8;
typedef __attribute__((ext_vector_type(4))) _Float16 f16x4;
typedef __attribute__((ext_vector_type(4))) float f32x4;

constexpr int B_ = 8, LQ = 1024, LK = 2048, NH = 16, HID = 1024;

// async global->LDS, 16B per lane; LDS dest must be wave-uniform base + lane*16
__device__ __forceinline__ void gll16(const void* g, void* l) {
  __builtin_amdgcn_global_load_lds((const __attribute__((address_space(1))) void*)g,
                                   (__attribute__((address_space(3))) void*)l, 16, 0, 0);
}

// DPP cross-lane helpers (no DS traffic)
__device__ __forceinline__ float rowmax16(float x) {
  float y;
  y = __int_as_float(__builtin_amdgcn_update_dpp(0, __float_as_int(x), 0x128, 0xf, 0xf, true)); // row_ror:8
  x = fmaxf(x, y);
  y = __int_as_float(__builtin_amdgcn_update_dpp(0, __float_as_int(x), 0x124, 0xf, 0xf, true)); // row_ror:4
  x = fmaxf(x, y);
  y = __int_as_float(__builtin_amdgcn_update_dpp(0, __float_as_int(x), 0x4E, 0xf, 0xf, true));  // quad_perm 2,3,0,1
  x = fmaxf(x, y);
  y = __int_as_float(__builtin_amdgcn_update_dpp(0, __float_as_int(x), 0xB1, 0xf, 0xf, true));  // quad_perm 1,0,3,2
  x = fmaxf(x, y);
  return x;
}
__device__ __forceinline__ float shx1(float x) {  // lane ^ 1
  return __int_as_float(__builtin_amdgcn_update_dpp(0, __float_as_int(x), 0xB1, 0xf, 0xf, true));
}

// ---------- fused fp32 -> fp16 cast for all 5 inputs ----------
__global__ __launch_bounds__(256) void cvt_all(const float* __restrict__ x, const float* __restrict__ y,
                                               const float* __restrict__ wq, const float* __restrict__ wkv,
                                               const float* __restrict__ wo, f16* __restrict__ xb,
                                               f16* __restrict__ yb, f16* __restrict__ wqb,
                                               f16* __restrict__ wkvb, f16* __restrict__ wob) {
  int t = blockIdx.x * 256 + threadIdx.x;  // in float4 units, total 7340032
  const float* s;
  f16* d;
  int off;
  if (t < 2097152) { s = x; d = xb; off = t; }
  else if (t < 6291456) { s = y; d = yb; off = t - 2097152; }
  else if (t < 6553600) { s = wq; d = wqb; off = t - 6291456; }
  else if (t < 7077888) { s = wkv; d = wkvb; off = t - 6553600; }
  else { s = wo; d = wob; off = t - 7077888; }
  float4 v = ((const float4*)s)[off];
  f16x4 o = {(f16)v.x, (f16)v.y, (f16)v.z, (f16)v.w};
  ((f16x4*)d)[off] = o;
}

// ---------- RoPE trig tables: tabQ = log2e*(cos,sin), tabK = (cos,sin) ----------
__global__ __launch_bounds__(256) void rope_tab(float2* __restrict__ tabQ, float2* __restrict__ tabK) {
  int t = blockIdx.x * 256 + threadIdx.x;  // 2048*32
  int pos = t >> 5, i = t & 31;
  float inv_t = exp2f((float)i * -0.41524101186091903f);
  float sn, cs;
  sincosf((float)pos * inv_t, &sn, &cs);
  tabK[t] = make_float2(cs, sn);
  const float L2E = 1.4426950408889634f;
  tabQ[t] = make_float2(cs * L2E, sn * L2E);
}

// ---------- fused NT GEMM: C[M,N] = A[M,K] * B[N,K]^T ----------
// MODE 0: Q proj -> RoPE (tab=tabQ, log2e-folded) -> Qb [bh][lq][64]
// MODE 1: KV proj -> wn=0: RoPE K (tab=tabK) -> Kb [bh][lk][64]; wn=1: V^T -> Vt [bh][kc][dv][64]
// MODE 2: plain fp32 output
template <int MODE>
__global__ __launch_bounds__(256) void gemm_fused(const f16* __restrict__ A,
                                                  const f16* __restrict__ Bm,
                                                  void* __restrict__ out0,
                                                  void* __restrict__ out1,
                                                  const float2* __restrict__ tab,
                                                  int M, int N, int K) {
  const int n0 = blockIdx.x * 128, m0 = blockIdx.y * 128;
  const int tid = threadIdx.x, lane = tid & 63, w = tid >> 6;
  const int wm = w >> 1, wn = w & 1;
  const int quad = lane >> 4, l16 = lane & 15;
  __shared__ __align__(16) f16 As[128 * 64];
  __shared__ __align__(16) f16 Bs[128 * 64];
  f32x4 acc[4][4] = {};
  const int sr = tid >> 3, sc = (tid & 7) * 8;
  const f16* ga = A + (size_t)(m0 + sr) * K + sc;
  const f16* gb = Bm + (size_t)(n0 + sr) * K + sc;
  for (int k0 = 0; k0 < K; k0 += 64) {
    __syncthreads();
#pragma unroll
    for (int p = 0; p < 4; ++p) {
      gll16(ga + (size_t)p * 32 * K + k0, &As[(sr + p * 32) * 64 + sc]);
      gll16(gb + (size_t)p * 32 * K + k0, &Bs[(sr + p * 32) * 64 + sc]);
    }
    __syncthreads();
#pragma unroll
    for (int ks = 0; ks < 2; ++ks) {
      f16x8 af[4], bfr[4];
#pragma unroll
      for (int i = 0; i < 4; ++i) {
        af[i] = *(const f16x8*)&As[(wm * 64 + i * 16 + l16) * 64 + ks * 32 + quad * 8];
        bfr[i] = *(const f16x8*)&Bs[(wn * 64 + i * 16 + l16) * 64 + ks * 32 + quad * 8];
      }
#pragma unroll
      for (int i = 0; i < 4; ++i)
#pragma unroll
        for (int j = 0; j < 4; ++j)
          acc[i][j] = __builtin_amdgcn_mfma_f32_16x16x32_f16(af[i], bfr[j], acc[i][j], 0, 0, 0);
    }
  }
  if (MODE == 2) {
#pragma unroll
    for (int i = 0; i < 4; ++i)
#pragma unroll
      for (int j = 0; j < 4; ++j) {
        int row = m0 + wm * 64 + i * 16 + quad * 4;
        int col = n0 + wn * 64 + j * 16 + l16;
#pragma unroll
        for (int r = 0; r < 4; ++r)
          ((float*)out0)[(size_t)(row + r) * N + col] = acc[i][j][r];
      }
    return;
  }
  constexpr int LSH = (MODE == 0) ? 10 : 11;
  constexpr int LMSK = (MODE == 0) ? 1023 : 2047;
  const int Ltok = LMSK + 1;
  if (MODE == 0 || wn == 0) {
    // RoPE path via table
#pragma unroll
    for (int j = 0; j < 4; ++j) {
      int c = n0 + wn * 64 + j * 16 + l16;
      int h = (MODE == 0) ? (c >> 6) : (n0 >> 7);
      int d = (MODE == 0) ? (c & 63) : (j * 16 + l16);
      const float2* tcol = tab + (d >> 1);
#pragma unroll
      for (int i = 0; i < 4; ++i) {
        f32x4 v = acc[i][j];
        f32x4 pv;
#pragma unroll
        for (int r = 0; r < 4; ++r) pv[r] = shx1(v[r]);
        int row0 = m0 + wm * 64 + i * 16 + quad * 4;
#pragma unroll
        for (int r = 0; r < 4; ++r) {
          int row = row0 + r;
          int pos = row & LMSK, b = row >> LSH;
          float2 t = tcol[pos * 32];
          float o = (d & 1) ? (v[r] * t.x + pv[r] * t.y) : (v[r] * t.x - pv[r] * t.y);
          ((f16*)out0)[(((size_t)b * NH + h) * Ltok + pos) * 64 + d] = (f16)o;
        }
      }
    }
  } else {
    // V path: write V^T tiled: Vt[((bh*32 + kc)*64 + dv)*64 + klo]
    const int h = n0 >> 7;
#pragma unroll
    for (int j = 0; j < 4; ++j) {
      int dv = j * 16 + l16;
#pragma unroll
      for (int i = 0; i < 4; ++i) {
        int row0 = m0 + wm * 64 + i * 16 + quad * 4;
        int pos0 = row0 & 2047, b = row0 >> 11;
        int kc = pos0 >> 6, klo = pos0 & 63;
        f32x4 v = acc[i][j];
        f16x4 pk = {(f16)v[0], (f16)v[1], (f16)v[2], (f16)v[3]};
        *(f16x4*)&((f16*)out1)[((((size_t)b * NH + h) * 32 + kc) * 64 + dv) * 64 + klo] = pk;
      }
    }
  }
}

// ---------- flash attention ----------
// 1D grid of 1024 blocks, XCD-swizzled: bh = blk & 127 -> XCD = blk%8 = bh%8,
// so all 8 q-tile blocks of one bh land on the same XCD and share its K/V L2 stream.
// 4 waves; each wave: 2 q-tiles of 16 rows (128 q-rows/block).
// Qb pre-scaled by log2e; softmax in exp2 domain.
// __launch_bounds__(256,4): VGPR cap 128 — (256,5) in R4 capped at ~100 and the
// allocator spilled the accumulators to scratch (WRITE_SIZE 66MB->1.33GB). Keep 4.
__global__ __launch_bounds__(256, 4) void attn(const f16* __restrict__ Qb,
                                               const f16* __restrict__ Kb,
                                               const f16* __restrict__ Vt,
                                               f16* __restrict__ attnb) {
  const int bh = blockIdx.x & 127, b = bh >> 4, h = bh & 15;
  const int q0 = (blockIdx.x >> 7) * 128;
  const int tid = threadIdx.x, lane = tid & 63, w = tid >> 6;
  const int quad = lane >> 4, l16 = lane & 15;
  __shared__ __align__(16) f16 Ks[64 * 72];
  __shared__ __align__(16) f16 Vts[64 * 72];
  __shared__ __align__(16) f16 Ps[4][16 * 72];  // one slot per wave, reused by both q-tiles
  const f16* qp = Qb + ((size_t)bh * LQ + q0 + w * 32 + l16) * 64;
  f16x8 qa0 = *(const f16x8*)&qp[quad * 8];
  f16x8 qa1 = *(const f16x8*)&qp[32 + quad * 8];
  f16x8 qb0 = *(const f16x8*)&qp[16 * 64 + quad * 8];
  f16x8 qb1 = *(const f16x8*)&qp[16 * 64 + 32 + quad * 8];
  f16x8 onesv;
#pragma unroll
  for (int j = 0; j < 8; ++j) onesv[j] = (f16)1.0f;
  f32x4 o0[4] = {}, o1[4] = {};
  f32x4 la0 = {}, la1 = {};
  float mr0[4], mr1[4];
#pragma unroll
  for (int r = 0; r < 4; ++r) { mr0[r] = -1e30f; mr1[r] = -1e30f; }
  const f16* kbase = Kb + (size_t)bh * LK * 64;
  const f16* vtb = Vt + (size_t)bh * 32 * 4096;

  for (int c = 0; c < LK / 64; ++c) {
    int kc0 = c * 64;
    __syncthreads();
#pragma unroll
    for (int p = 0; p < 2; ++p) {
      int r = (tid >> 3) + p * 32, s = tid & 7;
      *(uint4*)&Ks[r * 72 + s * 8] = *(const uint4*)&kbase[(size_t)(kc0 + r) * 64 + s * 8];
      *(uint4*)&Vts[r * 72 + s * 8] = *(const uint4*)&vtb[(size_t)(c * 64 + r) * 64 + s * 8];
    }
    __syncthreads();
    // S = Q K^T for both q-tiles, sharing K fragments
    f32x4 s0[4] = {}, s1[4] = {};
#pragma unroll
    for (int nt = 0; nt < 4; ++nt) {
      f16x8 kf0 = *(const f16x8*)&Ks[(nt * 16 + l16) * 72 + quad * 8];
      f16x8 kf1 = *(const f16x8*)&Ks[(nt * 16 + l16) * 72 + 32 + quad * 8];
      s0[nt] = __builtin_amdgcn_mfma_f32_16x16x32_f16(qa0, kf0, s0[nt], 0, 0, 0);
      s0[nt] = __builtin_amdgcn_mfma_f32_16x16x32_f16(qa1, kf1, s0[nt], 0, 0, 0);
      s1[nt] = __builtin_amdgcn_mfma_f32_16x16x32_f16(qb0, kf0, s1[nt], 0, 0, 0);
      s1[nt] = __builtin_amdgcn_mfma_f32_16x16x32_f16(qb1, kf1, s1[nt], 0, 0, 0);
    }
    // online softmax (exp2 domain), C/D layout: row=quad*4+r, col=nt*16+l16
    auto softmax = [&](f32x4* s, float* mr, f32x4& la, f32x4* o) {
#pragma unroll
      for (int r = 0; r < 4; ++r) {
        float mx = fmaxf(fmaxf(s[0][r], s[1][r]), fmaxf(s[2][r], s[3][r]));
        mx = rowmax16(mx);
        if (mx > mr[r]) {
          float al = exp2f(mr[r] - mx);
          mr[r] = mx;
          la[r] *= al;
#pragma unroll
          for (int dt = 0; dt < 4; ++dt) o[dt][r] *= al;
        }
#pragma unroll
        for (int nt = 0; nt < 4; ++nt)
          Ps[w][(quad * 4 + r) * 72 + nt * 16 + l16] = (f16)exp2f(s[nt][r] - mr[r]);
      }
    };
    // tile 0: write P, read frags (same LDS slot reused for tile 1 after)
    softmax(s0, mr0, la0, o0);
    f16x8 p00 = *(const f16x8*)&Ps[w][l16 * 72 + quad * 8];
    f16x8 p01 = *(const f16x8*)&Ps[w][l16 * 72 + 32 + quad * 8];
    softmax(s1, mr1, la1, o1);
    f16x8 p10 = *(const f16x8*)&Ps[w][l16 * 72 + quad * 8];
    f16x8 p11 = *(const f16x8*)&Ps[w][l16 * 72 + 32 + quad * 8];
    // row sums via ones-MFMA (same C/D layout as o)
    la0 = __builtin_amdgcn_mfma_f32_16x16x32_f16(p00, onesv, la0, 0, 0, 0);
    la0 = __builtin_amdgcn_mfma_f32_16x16x32_f16(p01, onesv, la0, 0, 0, 0);
    la1 = __builtin_amdgcn_mfma_f32_16x16x32_f16(p10, onesv, la1, 0, 0, 0);
    la1 = __builtin_amdgcn_mfma_f32_16x16x32_f16(p11, onesv, la1, 0, 0, 0);
    // O += P V, sharing V fragments across both q-tiles
#pragma unroll
    for (int dt = 0; dt < 4; ++dt) {
      f16x8 vf0 = *(const f16x8*)&Vts[(dt * 16 + l16) * 72 + quad * 8];
      f16x8 vf1 = *(const f16x8*)&Vts[(dt * 16 + l16) * 72 + 32 + quad * 8];
      o0[dt] = __builtin_amdgcn_mfma_f32_16x16x32_f16(p00, vf0, o0[dt], 0, 0, 0);
      o0[dt] = __builtin_amdgcn_mfma_f32_16x16x32_f16(p01, vf1, o0[dt], 0, 0, 0);
      o1[dt] = __builtin_amdgcn_mfma_f32_16x16x32_f16(p10, vf0, o1[dt], 0, 0, 0);
      o1[dt] = __builtin_amdgcn_mfma_f32_16x16x32_f16(p11, vf1, o1[dt], 0, 0, 0);
    }
  }
#pragma unroll
  for (int dt = 0; dt < 4; ++dt)
#pragma unroll
    for (int r = 0; r < 4; ++r) {
      int qA = q0 + w * 32 + quad * 4 + r;
      int dv = dt * 16 + l16;
      attnb[((size_t)b * LQ + qA) * HID + h * 64 + dv] = (f16)(o0[dt][r] / la0[r]);
      attnb[((size_t)b * LQ + qA + 16) * HID + h * 64 + dv] = (f16)(o1[dt][r] / la1[r]);
    }
}

extern "C" void kernel_launch(void* const* d_in, const int* in_sizes, int n_in,
                              void* d_out, int out_size, void* d_ws, size_t ws_size,
                              hipStream_t stream) {
  const float* x = (const float*)d_in[0];
  const float* y = (const float*)d_in[1];
  const float* Wq = (const float*)d_in[2];
  const float* Wkv = (const float*)d_in[3];
  const float* Wo = (const float*)d_in[4];
  float* out = (float*)d_out;

  char* p = (char*)d_ws;
  f16* xb = (f16*)p;    p += (size_t)B_ * LQ * HID * 2;      // 16 MB
  f16* yb = (f16*)p;    p += (size_t)B_ * LK * HID * 2;      // 32 MB
  f16* Wqb = (f16*)p;   p += (size_t)HID * HID * 2;          // 2 MB
  f16* Wkvb = (f16*)p;  p += (size_t)2 * HID * HID * 2;      // 4 MB
  f16* Wob = (f16*)p;   p += (size_t)HID * HID * 2;          // 2 MB
  f16* Qb = (f16*)p;    p += (size_t)B_ * LQ * HID * 2;      // 16 MB
  f16* Kb = (f16*)p;    p += (size_t)B_ * LK * HID * 2;      // 32 MB
  f16* Vt = (f16*)p;    p += (size_t)B_ * LK * HID * 2;      // 32 MB
  f16* attnb = xb;  // xb dead after GEMM1
  // RoPE tables live in d_out scratch (dead before the final GEMM overwrites d_out)
  float2* tabQ = (float2*)d_out;
  float2* tabK = tabQ + 2048 * 32;

  cvt_all<<<dim3(28672), 256, 0, stream>>>(x, y, Wq, Wkv, Wo, xb, yb, Wqb, Wkvb, Wob);
  rope_tab<<<dim3(256), 256, 0, stream>>>(tabQ, tabK);

  // Q = RoPE(x @ Wq^T) * log2e -> Qb [bh][lq][64]
  gemm_fused<0><<<dim3(HID / 128, B_ * LQ / 128), 256, 0, stream>>>(
      xb, Wqb, Qb, nullptr, tabQ, B_ * LQ, HID, HID);
  // KV = y @ Wkv^T -> Kb (RoPE) + Vt (transposed, chunk-tiled)
  gemm_fused<1><<<dim3(2 * HID / 128, B_ * LK / 128), 256, 0, stream>>>(
      yb, Wkvb, Kb, Vt, tabK, B_ * LK, 2 * HID, HID);

  // attention -> attnb [B*LQ, 1024] fp16, XCD-swizzled 1D grid
  attn<<<dim3(1024), 256, 0, stream>>>(Qb, Kb, Vt, attnb);

  // out = attn @ Wo^T -> fp32
  gemm_fused<2><<<dim3(HID / 128, B_ * LQ / 128), 256, 0, stream>>>(
      attnb, Wob, out, nullptr, nullptr, B_ * LQ, HID, HID);
}

// Round 6
// 526.076 us; speedup vs baseline: 1.6994x; 1.0039x over previous
//
#include <hip/hip_runtime.h>

typedef _Float16 f16;
typedef __attribute__((ext_vector_type(8))) _Float16 f16x8;
typedef __attribute__((ext_vector_type(4))) _Float16 f16x4;
typedef __attribute__((ext_vector_type(4))) float f32x4;

constexpr int B_ = 8, LQ = 1024, LK = 2048, NH = 16, HID = 1024;

// async global->LDS, 16B per lane; LDS dest must be wave-uniform base + lane*16
__device__ __forceinline__ void gll16(const void* g, void* l) {
  __builtin_amdgcn_global_load_lds((const __attribute__((address_space(1))) void*)g,
                                   (__attribute__((address_space(3))) void*)l, 16, 0, 0);
}

// DPP cross-lane helpers (no DS traffic)
__device__ __forceinline__ float rowmax16(float x) {
  float y;
  y = __int_as_float(__builtin_amdgcn_update_dpp(0, __float_as_int(x), 0x128, 0xf, 0xf, true)); // row_ror:8
  x = fmaxf(x, y);
  y = __int_as_float(__builtin_amdgcn_update_dpp(0, __float_as_int(x), 0x124, 0xf, 0xf, true)); // row_ror:4
  x = fmaxf(x, y);
  y = __int_as_float(__builtin_amdgcn_update_dpp(0, __float_as_int(x), 0x4E, 0xf, 0xf, true));  // quad_perm 2,3,0,1
  x = fmaxf(x, y);
  y = __int_as_float(__builtin_amdgcn_update_dpp(0, __float_as_int(x), 0xB1, 0xf, 0xf, true));  // quad_perm 1,0,3,2
  x = fmaxf(x, y);
  return x;
}
__device__ __forceinline__ float shx1(float x) {  // lane ^ 1
  return __int_as_float(__builtin_amdgcn_update_dpp(0, __float_as_int(x), 0xB1, 0xf, 0xf, true));
}

// ---------- fused fp32 -> fp16 cast for all 5 inputs + RoPE trig tables ----------
__global__ __launch_bounds__(256) void cvt_all(const float* __restrict__ x, const float* __restrict__ y,
                                               const float* __restrict__ wq, const float* __restrict__ wkv,
                                               const float* __restrict__ wo, f16* __restrict__ xb,
                                               f16* __restrict__ yb, f16* __restrict__ wqb,
                                               f16* __restrict__ wkvb, f16* __restrict__ wob,
                                               float2* __restrict__ tabQ, float2* __restrict__ tabK) {
  int t = blockIdx.x * 256 + threadIdx.x;  // in float4 units, total 7340032 + 65536 table threads
  if (t >= 7340032) {
    int u = t - 7340032;  // 2048*32
    int pos = u >> 5, i = u & 31;
    float inv_t = exp2f((float)i * -0.41524101186091903f);
    float sn, cs;
    sincosf((float)pos * inv_t, &sn, &cs);
    tabK[u] = make_float2(cs, sn);
    const float L2E = 1.4426950408889634f;
    tabQ[u] = make_float2(cs * L2E, sn * L2E);
    return;
  }
  const float* s;
  f16* d;
  int off;
  if (t < 2097152) { s = x; d = xb; off = t; }
  else if (t < 6291456) { s = y; d = yb; off = t - 2097152; }
  else if (t < 6553600) { s = wq; d = wqb; off = t - 6291456; }
  else if (t < 7077888) { s = wkv; d = wkvb; off = t - 6553600; }
  else { s = wo; d = wob; off = t - 7077888; }
  float4 v = ((const float4*)s)[off];
  f16x4 o = {(f16)v.x, (f16)v.y, (f16)v.z, (f16)v.w};
  ((f16x4*)d)[off] = o;
}

// ---------- fused NT GEMM: C[M,N] = A[M,K] * B[N,K]^T ----------
// MODE 0: Q proj -> RoPE (tab=tabQ, log2e-folded) -> Qb [bh][lq][64]
// MODE 1: KV proj -> wn=0: RoPE K (tab=tabK) -> Kb [bh][lk][64]; wn=1: V^T -> Vt [bh][kc][dv][64]
// MODE 2: plain fp32 output
template <int MODE>
__global__ __launch_bounds__(256) void gemm_fused(const f16* __restrict__ A,
                                                  const f16* __restrict__ Bm,
                                                  void* __restrict__ out0,
                                                  void* __restrict__ out1,
                                                  const float2* __restrict__ tab,
                                                  int M, int N, int K) {
  const int n0 = blockIdx.x * 128, m0 = blockIdx.y * 128;
  const int tid = threadIdx.x, lane = tid & 63, w = tid >> 6;
  const int wm = w >> 1, wn = w & 1;
  const int quad = lane >> 4, l16 = lane & 15;
  __shared__ __align__(16) f16 As[128 * 64];
  __shared__ __align__(16) f16 Bs[128 * 64];
  f32x4 acc[4][4] = {};
  const int sr = tid >> 3, sc = (tid & 7) * 8;
  const f16* ga = A + (size_t)(m0 + sr) * K + sc;
  const f16* gb = Bm + (size_t)(n0 + sr) * K + sc;
  for (int k0 = 0; k0 < K; k0 += 64) {
    __syncthreads();
#pragma unroll
    for (int p = 0; p < 4; ++p) {
      gll16(ga + (size_t)p * 32 * K + k0, &As[(sr + p * 32) * 64 + sc]);
      gll16(gb + (size_t)p * 32 * K + k0, &Bs[(sr + p * 32) * 64 + sc]);
    }
    __syncthreads();
#pragma unroll
    for (int ks = 0; ks < 2; ++ks) {
      f16x8 af[4], bfr[4];
#pragma unroll
      for (int i = 0; i < 4; ++i) {
        af[i] = *(const f16x8*)&As[(wm * 64 + i * 16 + l16) * 64 + ks * 32 + quad * 8];
        bfr[i] = *(const f16x8*)&Bs[(wn * 64 + i * 16 + l16) * 64 + ks * 32 + quad * 8];
      }
#pragma unroll
      for (int i = 0; i < 4; ++i)
#pragma unroll
        for (int j = 0; j < 4; ++j)
          acc[i][j] = __builtin_amdgcn_mfma_f32_16x16x32_f16(af[i], bfr[j], acc[i][j], 0, 0, 0);
    }
  }
  if (MODE == 2) {
#pragma unroll
    for (int i = 0; i < 4; ++i)
#pragma unroll
      for (int j = 0; j < 4; ++j) {
        int row = m0 + wm * 64 + i * 16 + quad * 4;
        int col = n0 + wn * 64 + j * 16 + l16;
#pragma unroll
        for (int r = 0; r < 4; ++r)
          ((float*)out0)[(size_t)(row + r) * N + col] = acc[i][j][r];
      }
    return;
  }
  constexpr int LSH = (MODE == 0) ? 10 : 11;
  constexpr int LMSK = (MODE == 0) ? 1023 : 2047;
  const int Ltok = LMSK + 1;
  if (MODE == 0 || wn == 0) {
    // RoPE path via table
#pragma unroll
    for (int j = 0; j < 4; ++j) {
      int c = n0 + wn * 64 + j * 16 + l16;
      int h = (MODE == 0) ? (c >> 6) : (n0 >> 7);
      int d = (MODE == 0) ? (c & 63) : (j * 16 + l16);
      const float2* tcol = tab + (d >> 1);
#pragma unroll
      for (int i = 0; i < 4; ++i) {
        f32x4 v = acc[i][j];
        f32x4 pv;
#pragma unroll
        for (int r = 0; r < 4; ++r) pv[r] = shx1(v[r]);
        int row0 = m0 + wm * 64 + i * 16 + quad * 4;
#pragma unroll
        for (int r = 0; r < 4; ++r) {
          int row = row0 + r;
          int pos = row & LMSK, b = row >> LSH;
          float2 t = tcol[pos * 32];
          float o = (d & 1) ? (v[r] * t.x + pv[r] * t.y) : (v[r] * t.x - pv[r] * t.y);
          ((f16*)out0)[(((size_t)b * NH + h) * Ltok + pos) * 64 + d] = (f16)o;
        }
      }
    }
  } else {
    // V path: write V^T tiled: Vt[((bh*32 + kc)*64 + dv)*64 + klo]
    const int h = n0 >> 7;
#pragma unroll
    for (int j = 0; j < 4; ++j) {
      int dv = j * 16 + l16;
#pragma unroll
      for (int i = 0; i < 4; ++i) {
        int row0 = m0 + wm * 64 + i * 16 + quad * 4;
        int pos0 = row0 & 2047, b = row0 >> 11;
        int kc = pos0 >> 6, klo = pos0 & 63;
        f32x4 v = acc[i][j];
        f16x4 pk = {(f16)v[0], (f16)v[1], (f16)v[2], (f16)v[3]};
        *(f16x4*)&((f16*)out1)[((((size_t)b * NH + h) * 32 + kc) * 64 + dv) * 64 + klo] = pk;
      }
    }
  }
}

// ---------- flash attention ----------
// 1D grid of 1024 blocks (4/CU): bh = blk & 127, q-tile = blk >> 7.
// 4 waves; each wave: 2 q-tiles of 16 rows (128 q-rows/block).
// Qb pre-scaled by log2e; softmax in exp2 domain, branchless rescale.
// Register-double-buffered K/V staging; dual Ps slots per wave (no intra-chunk
// LDS reuse serialization). __launch_bounds__(256,4): VGPR cap 128 (R4: (256,5)
// capped ~100 -> spilled accumulators, WRITE 66MB->1.33GB).
__global__ __launch_bounds__(256, 4) void attn(const f16* __restrict__ Qb,
                                               const f16* __restrict__ Kb,
                                               const f16* __restrict__ Vt,
                                               f16* __restrict__ attnb) {
  const int bh = blockIdx.x & 127, b = bh >> 4, h = bh & 15;
  const int q0 = (blockIdx.x >> 7) * 128;
  const int tid = threadIdx.x, lane = tid & 63, w = tid >> 6;
  const int quad = lane >> 4, l16 = lane & 15;
  __shared__ __align__(16) f16 Ks[64 * 72];
  __shared__ __align__(16) f16 Vts[64 * 72];
  __shared__ __align__(16) f16 Ps[8][16 * 72];  // two slots per wave
  const f16* qp = Qb + ((size_t)bh * LQ + q0 + w * 32 + l16) * 64;
  f16x8 qa0 = *(const f16x8*)&qp[quad * 8];
  f16x8 qa1 = *(const f16x8*)&qp[32 + quad * 8];
  f16x8 qb0 = *(const f16x8*)&qp[16 * 64 + quad * 8];
  f16x8 qb1 = *(const f16x8*)&qp[16 * 64 + 32 + quad * 8];
  f16x8 onesv;
#pragma unroll
  for (int j = 0; j < 8; ++j) onesv[j] = (f16)1.0f;
  f32x4 o0[4] = {}, o1[4] = {};
  f32x4 la0 = {}, la1 = {};
  float mr0[4], mr1[4];
#pragma unroll
  for (int r = 0; r < 4; ++r) { mr0[r] = -1e30f; mr1[r] = -1e30f; }
  const f16* kbase = Kb + (size_t)bh * LK * 64;
  const f16* vtb = Vt + (size_t)bh * 32 * 4096;
  const int sro = (tid >> 3), sco = (tid & 7) * 8;

  // register double-buffer: preload chunk 0
  uint4 rk[2], rv[2];
#pragma unroll
  for (int p = 0; p < 2; ++p) {
    rk[p] = *(const uint4*)&kbase[(size_t)(sro + p * 32) * 64 + sco];
    rv[p] = *(const uint4*)&vtb[(size_t)(sro + p * 32) * 64 + sco];
  }

  for (int c = 0; c < LK / 64; ++c) {
    __syncthreads();
#pragma unroll
    for (int p = 0; p < 2; ++p) {
      *(uint4*)&Ks[(sro + p * 32) * 72 + sco] = rk[p];
      *(uint4*)&Vts[(sro + p * 32) * 72 + sco] = rv[p];
    }
    __syncthreads();
    if (c + 1 < LK / 64) {
      int nc0 = (c + 1) * 64;
#pragma unroll
      for (int p = 0; p < 2; ++p) {
        rk[p] = *(const uint4*)&kbase[(size_t)(nc0 + sro + p * 32) * 64 + sco];
        rv[p] = *(const uint4*)&vtb[(size_t)(nc0 + sro + p * 32) * 64 + sco];
      }
    }
    // S = Q K^T for both q-tiles, sharing K fragments
    f32x4 s0[4] = {}, s1[4] = {};
#pragma unroll
    for (int nt = 0; nt < 4; ++nt) {
      f16x8 kf0 = *(const f16x8*)&Ks[(nt * 16 + l16) * 72 + quad * 8];
      f16x8 kf1 = *(const f16x8*)&Ks[(nt * 16 + l16) * 72 + 32 + quad * 8];
      s0[nt] = __builtin_amdgcn_mfma_f32_16x16x32_f16(qa0, kf0, s0[nt], 0, 0, 0);
      s0[nt] = __builtin_amdgcn_mfma_f32_16x16x32_f16(qa1, kf1, s0[nt], 0, 0, 0);
      s1[nt] = __builtin_amdgcn_mfma_f32_16x16x32_f16(qb0, kf0, s1[nt], 0, 0, 0);
      s1[nt] = __builtin_amdgcn_mfma_f32_16x16x32_f16(qb1, kf1, s1[nt], 0, 0, 0);
    }
    // online softmax (exp2 domain), branchless; C/D layout: row=quad*4+r, col=nt*16+l16
    auto softmax = [&](f32x4* s, float* mr, f32x4& la, f32x4* o, int slot) {
#pragma unroll
      for (int r = 0; r < 4; ++r) {
        float mx = fmaxf(fmaxf(s[0][r], s[1][r]), fmaxf(s[2][r], s[3][r]));
        mx = rowmax16(mx);
        float mn = fmaxf(mr[r], mx);
        float al = exp2f(mr[r] - mn);
        mr[r] = mn;
        la[r] *= al;
#pragma unroll
        for (int dt = 0; dt < 4; ++dt) o[dt][r] *= al;
#pragma unroll
        for (int nt = 0; nt < 4; ++nt)
          Ps[slot][(quad * 4 + r) * 72 + nt * 16 + l16] = (f16)exp2f(s[nt][r] - mn);
      }
    };
    softmax(s0, mr0, la0, o0, w * 2);
    softmax(s1, mr1, la1, o1, w * 2 + 1);
    f16x8 p00 = *(const f16x8*)&Ps[w * 2][l16 * 72 + quad * 8];
    f16x8 p01 = *(const f16x8*)&Ps[w * 2][l16 * 72 + 32 + quad * 8];
    f16x8 p10 = *(const f16x8*)&Ps[w * 2 + 1][l16 * 72 + quad * 8];
    f16x8 p11 = *(const f16x8*)&Ps[w * 2 + 1][l16 * 72 + 32 + quad * 8];
    // row sums via ones-MFMA (same C/D layout as o)
    la0 = __builtin_amdgcn_mfma_f32_16x16x32_f16(p00, onesv, la0, 0, 0, 0);
    la0 = __builtin_amdgcn_mfma_f32_16x16x32_f16(p01, onesv, la0, 0, 0, 0);
    la1 = __builtin_amdgcn_mfma_f32_16x16x32_f16(p10, onesv, la1, 0, 0, 0);
    la1 = __builtin_amdgcn_mfma_f32_16x16x32_f16(p11, onesv, la1, 0, 0, 0);
    // O += P V, sharing V fragments across both q-tiles
#pragma unroll
    for (int dt = 0; dt < 4; ++dt) {
      f16x8 vf0 = *(const f16x8*)&Vts[(dt * 16 + l16) * 72 + quad * 8];
      f16x8 vf1 = *(const f16x8*)&Vts[(dt * 16 + l16) * 72 + 32 + quad * 8];
      o0[dt] = __builtin_amdgcn_mfma_f32_16x16x32_f16(p00, vf0, o0[dt], 0, 0, 0);
      o0[dt] = __builtin_amdgcn_mfma_f32_16x16x32_f16(p01, vf1, o0[dt], 0, 0, 0);
      o1[dt] = __builtin_amdgcn_mfma_f32_16x16x32_f16(p10, vf0, o1[dt], 0, 0, 0);
      o1[dt] = __builtin_amdgcn_mfma_f32_16x16x32_f16(p11, vf1, o1[dt], 0, 0, 0);
    }
  }
#pragma unroll
  for (int dt = 0; dt < 4; ++dt)
#pragma unroll
    for (int r = 0; r < 4; ++r) {
      int qA = q0 + w * 32 + quad * 4 + r;
      int dv = dt * 16 + l16;
      attnb[((size_t)b * LQ + qA) * HID + h * 64 + dv] = (f16)(o0[dt][r] / la0[r]);
      attnb[((size_t)b * LQ + qA + 16) * HID + h * 64 + dv] = (f16)(o1[dt][r] / la1[r]);
    }
}

extern "C" void kernel_launch(void* const* d_in, const int* in_sizes, int n_in,
                              void* d_out, int out_size, void* d_ws, size_t ws_size,
                              hipStream_t stream) {
  const float* x = (const float*)d_in[0];
  const float* y = (const float*)d_in[1];
  const float* Wq = (const float*)d_in[2];
  const float* Wkv = (const float*)d_in[3];
  const float* Wo = (const float*)d_in[4];
  float* out = (float*)d_out;

  char* p = (char*)d_ws;
  f16* xb = (f16*)p;    p += (size_t)B_ * LQ * HID * 2;      // 16 MB
  f16* yb = (f16*)p;    p += (size_t)B_ * LK * HID * 2;      // 32 MB
  f16* Wqb = (f16*)p;   p += (size_t)HID * HID * 2;          // 2 MB
  f16* Wkvb = (f16*)p;  p += (size_t)2 * HID * HID * 2;      // 4 MB
  f16* Wob = (f16*)p;   p += (size_t)HID * HID * 2;          // 2 MB
  f16* Qb = (f16*)p;    p += (size_t)B_ * LQ * HID * 2;      // 16 MB
  f16* Kb = (f16*)p;    p += (size_t)B_ * LK * HID * 2;      // 32 MB
  f16* Vt = (f16*)p;    p += (size_t)B_ * LK * HID * 2;      // 32 MB
  f16* attnb = xb;  // xb dead after GEMM1
  // RoPE tables live in d_out scratch (dead before the final GEMM overwrites d_out)
  float2* tabQ = (float2*)d_out;
  float2* tabK = tabQ + 2048 * 32;

  cvt_all<<<dim3(28928), 256, 0, stream>>>(x, y, Wq, Wkv, Wo, xb, yb, Wqb, Wkvb, Wob, tabQ, tabK);

  // Q = RoPE(x @ Wq^T) * log2e -> Qb [bh][lq][64]
  gemm_fused<0><<<dim3(HID / 128, B_ * LQ / 128), 256, 0, stream>>>(
      xb, Wqb, Qb, nullptr, tabQ, B_ * LQ, HID, HID);
  // KV = y @ Wkv^T -> Kb (RoPE) + Vt (transposed, chunk-tiled)
  gemm_fused<1><<<dim3(2 * HID / 128, B_ * LK / 128), 256, 0, stream>>>(
      yb, Wkvb, Kb, Vt, tabK, B_ * LK, 2 * HID, HID);

  // attention -> attnb [B*LQ, 1024] fp16, XCD-swizzled 1D grid
  attn<<<dim3(1024), 256, 0, stream>>>(Qb, Kb, Vt, attnb);

  // out = attn @ Wo^T -> fp32
  gemm_fused<2><<<dim3(HID / 128, B_ * LQ / 128), 256, 0, stream>>>(
      attnb, Wob, out, nullptr, nullptr, B_ * LQ, HID, HID);
}